// Round 3
// baseline (345.942 us; speedup 1.0000x reference)
//
#include <hip/hip_runtime.h>
#include <stdint.h>

typedef short short8 __attribute__((ext_vector_type(8)));
typedef float f32x4 __attribute__((ext_vector_type(4)));
typedef unsigned short ushort4v __attribute__((ext_vector_type(4)));
typedef unsigned int uint4v __attribute__((ext_vector_type(4)));
typedef unsigned long long u64;

#if __has_builtin(__builtin_amdgcn_exp2f)
#define EXP2(x) __builtin_amdgcn_exp2f(x)
#else
#define EXP2(x) exp2f(x)
#endif

// f32 -> bf16 round-to-nearest-even
__device__ __forceinline__ unsigned short f2bf(float f) {
  union { float f; unsigned u; } v; v.f = f;
  unsigned r = v.u + 0x7fffu + ((v.u >> 16) & 1u);
  return (unsigned short)(r >> 16);
}

// packed f32x2 -> bf16x2 (lo -> bits[15:0], hi -> bits[31:16])
__device__ __forceinline__ unsigned cvt_pk_bf16(float lo, float hi) {
  unsigned r;
  asm("v_cvt_pk_bf16_f32 %0, %1, %2" : "=v"(r) : "v"(lo), "v"(hi));
  return r;
}

// async global->LDS, 16B per lane; lds dst is wave-uniform base + lane*16
__device__ __forceinline__ void gld_lds16(const void* g, void* l) {
  __builtin_amdgcn_global_load_lds((const __attribute__((address_space(1))) void*)g,
                                   (__attribute__((address_space(3))) void*)l, 16, 0, 0);
}

// ---------------- fused prep: rope+casts | mask bit-pack | weight casts ----------------
// blocks [0,4096)        : RoPE q,k -> bf16 + value f32->bf16 cast
// blocks [4096,36864)    : mask -> per-lane-ownership bit pack
// blocks [36864,40960)   : 4x weight f32->bf16 cast
//
// mask pack layout: u64 word w = (b*1024+q)*16 + ktb*2 + gh  (gh = g>>1).
// Bit j of word: glo=j>>5, nt=(j&31)>>2, r=j&3, g=gh*2+glo, k = nt*16+g*4+r.
// flash lane(fr,g) loads word (qrow*16 + ktb*2 + (g>>1)), takes the 32-bit half
// selected by (g&1); bit (nt*4+r) masks its score S[q=fr][k=nt*16+g*4+r].
__global__ void prep_kernel(const float* __restrict__ q, const float* __restrict__ k,
                            const float* __restrict__ v,
                            const float* __restrict__ cs, const float* __restrict__ sn,
                            unsigned short* __restrict__ qo, unsigned short* __restrict__ ko,
                            unsigned short* __restrict__ vo,
                            const int* __restrict__ mask, u64* __restrict__ bits,
                            const float* __restrict__ s0, const float* __restrict__ s1,
                            const float* __restrict__ s2, const float* __restrict__ s3,
                            unsigned short* __restrict__ d0, unsigned short* __restrict__ d1,
                            unsigned short* __restrict__ d2, unsigned short* __restrict__ d3) {
  const int bx = blockIdx.x;
  if (bx < 4096) {
    const int idx = bx * 256 + threadIdx.x;
    const int p   = idx & 7;
    const int bth = idx >> 3;
    const int t   = (bth >> 4) & 1023;
    const size_t base = (size_t)bth * 64;
    const int dd0 = p * 4;

    const float4 x0 = *(const float4*)(q + base + dd0);
    const float4 x1 = *(const float4*)(q + base + dd0 + 32);
    const float4 y0 = *(const float4*)(k + base + dd0);
    const float4 y1 = *(const float4*)(k + base + dd0 + 32);
    const float4 c0 = *(const float4*)(cs + t * 64 + dd0);
    const float4 c1 = *(const float4*)(cs + t * 64 + dd0 + 32);
    const float4 sl = *(const float4*)(sn + t * 64 + dd0);
    const float4 sh = *(const float4*)(sn + t * 64 + dd0 + 32);

    ushort4v qlo, qhi, klo, khi;
    qlo[0]=f2bf(x0.x*c0.x - x1.x*sl.x); qlo[1]=f2bf(x0.y*c0.y - x1.y*sl.y);
    qlo[2]=f2bf(x0.z*c0.z - x1.z*sl.z); qlo[3]=f2bf(x0.w*c0.w - x1.w*sl.w);
    qhi[0]=f2bf(x1.x*c1.x + x0.x*sh.x); qhi[1]=f2bf(x1.y*c1.y + x0.y*sh.y);
    qhi[2]=f2bf(x1.z*c1.z + x0.z*sh.z); qhi[3]=f2bf(x1.w*c1.w + x0.w*sh.w);
    klo[0]=f2bf(y0.x*c0.x - y1.x*sl.x); klo[1]=f2bf(y0.y*c0.y - y1.y*sl.y);
    klo[2]=f2bf(y0.z*c0.z - y1.z*sl.z); klo[3]=f2bf(y0.w*c0.w - y1.w*sl.w);
    khi[0]=f2bf(y1.x*c1.x + y0.x*sh.x); khi[1]=f2bf(y1.y*c1.y + y0.y*sh.y);
    khi[2]=f2bf(y1.z*c1.z + y0.z*sh.z); khi[3]=f2bf(y1.w*c1.w + y0.w*sh.w);

    *(ushort4v*)(qo + base + dd0)      = qlo;
    *(ushort4v*)(qo + base + dd0 + 32) = qhi;
    *(ushort4v*)(ko + base + dd0)      = klo;
    *(ushort4v*)(ko + base + dd0 + 32) = khi;

    const size_t vb = (size_t)idx * 8;
    const float4 va = *(const float4*)(v + vb);
    const float4 vbv = *(const float4*)(v + vb + 4);
    ushort4v oa, ob;
    oa[0]=f2bf(va.x); oa[1]=f2bf(va.y); oa[2]=f2bf(va.z); oa[3]=f2bf(va.w);
    ob[0]=f2bf(vbv.x); ob[1]=f2bf(vbv.y); ob[2]=f2bf(vbv.z); ob[3]=f2bf(vbv.w);
    *(ushort4v*)(vo + vb)     = oa;
    *(ushort4v*)(vo + vb + 4) = ob;
  } else if (bx < 36864) {
    const int tid = (bx - 4096) * 256 + threadIdx.x;
    const int w = tid >> 6, j = tid & 63;
    const int gh = w & 1, ktb = (w >> 1) & 7, bq = w >> 4;
    const int nt = (j >> 2) & 7, r = j & 3, g = gh * 2 + (j >> 5);
    const int kk = nt * 16 + g * 4 + r;
    const int mv = mask[(size_t)bq * 1024 + ktb * 128 + kk];
    const u64 b = __ballot(mv != 0);
    if (j == 0) bits[w] = b;
  } else {
    const int idx2 = bx - 36864;
    const int m = idx2 >> 10;
    const float* src = (m == 0) ? s0 : (m == 1) ? s1 : (m == 2) ? s2 : s3;
    unsigned short* dst = (m == 0) ? d0 : (m == 1) ? d1 : (m == 2) ? d2 : d3;
    const int i = (idx2 & 1023) * 256 + threadIdx.x;
    const float4 vv = *(const float4*)(src + (size_t)i * 4);
    ushort4v o;
    o[0]=f2bf(vv.x); o[1]=f2bf(vv.y); o[2]=f2bf(vv.z); o[3]=f2bf(vv.w);
    *(ushort4v*)(dst + (size_t)i * 4) = o;
  }
}

// ---------------- merged QKV GEMM (one dispatch, z selects operand set) ----------------
// C[m,n] = (sum_k A[m,k]*B[n,k] + bias[n]) * scale
// z=0: Qp <- q_in x Wq  (scale folds 0.125*log2(e)), (b,h,t,d) bf16
// z=1: Kp <- k_in x Wk, (b,h,t,d) bf16
// z=2: Vp <- v_bf x Wv, (b,h,d,t') bf16 with t' k-permuted within 128-blocks to
//      match flash's register-resident P: k' = (nt&3)*32 + g*8 + (nt>>2)*4 + r.
__global__ __launch_bounds__(256, 4) void gemm_qkv(
    const unsigned short* __restrict__ Aq, const unsigned short* __restrict__ Ak,
    const unsigned short* __restrict__ Av,
    const unsigned short* __restrict__ Bq, const unsigned short* __restrict__ Bk,
    const unsigned short* __restrict__ Bv,
    const float* __restrict__ bq, const float* __restrict__ bk, const float* __restrict__ bv,
    unsigned short* __restrict__ Cq, unsigned short* __restrict__ Ck,
    unsigned short* __restrict__ Cv) {
  constexpr int K = 1024;
  const int z = blockIdx.z;
  const unsigned short* A  = (z == 0) ? Aq : (z == 1) ? Ak : Av;
  const unsigned short* Bw = (z == 0) ? Bq : (z == 1) ? Bk : Bv;
  const float* bias        = (z == 0) ? bq : (z == 1) ? bk : bv;
  unsigned short* Co       = (z == 0) ? Cq : (z == 1) ? Ck : Cv;
  const float scale = (z == 0) ? 0.18033688f : 1.0f;

  const int tid = threadIdx.x;
  const int wave = tid >> 6, lane = tid & 63;
  const int m0 = blockIdx.x * 128, n0 = blockIdx.y * 128;
  __shared__ unsigned short Asm[128 * 64];
  __shared__ unsigned short Bsm[128 * 64];
  f32x4 acc[4][4] = {};
  const int wr = (wave >> 1) * 64, wc = (wave & 1) * 64;
  const int ld_row = lane >> 3;
  const int ld_col = ((lane & 7) ^ ld_row) * 8;
  const int fr = lane & 15, g = lane >> 4;
  const int fr7 = fr & 7;

  for (int k0 = 0; k0 < K; k0 += 64) {
#pragma unroll
    for (int j = 0; j < 4; ++j) {
      const int c = j * 4 + wave;
      gld_lds16(A  + (size_t)(m0 + 8 * c + ld_row) * K + k0 + ld_col, &Asm[c * 512]);
      gld_lds16(Bw + (size_t)(n0 + 8 * c + ld_row) * K + k0 + ld_col, &Bsm[c * 512]);
    }
    __syncthreads();
#pragma unroll
    for (int ks = 0; ks < 2; ++ks) {
      const int ch = ((ks * 4 + g) ^ fr7) * 8;
      short8 af[4], bf[4];
#pragma unroll
      for (int i = 0; i < 4; ++i)
        af[i] = *(const short8*)&Asm[(wr + i * 16 + fr) * 64 + ch];
#pragma unroll
      for (int i = 0; i < 4; ++i)
        bf[i] = *(const short8*)&Bsm[(wc + i * 16 + fr) * 64 + ch];
#pragma unroll
      for (int i = 0; i < 4; ++i)
#pragma unroll
        for (int j = 0; j < 4; ++j)
          acc[i][j] = __builtin_amdgcn_mfma_f32_16x16x32_bf16(af[i], bf[j], acc[i][j], 0, 0, 0);
    }
    __syncthreads();
  }

#pragma unroll
  for (int i = 0; i < 4; ++i) {
    const int row_base = m0 + wr + i * 16 + g * 4;
#pragma unroll
    for (int j = 0; j < 4; ++j) {
      const int col = n0 + wc + j * 16 + fr;
      const float bval = bias[col];
      const int h_i = col >> 6, dd = col & 63;
      if (z < 2) {
#pragma unroll
        for (int r = 0; r < 4; ++r) {
          const int row = row_base + r;
          const int b_i = row >> 10, t_i = row & 1023;
          Co[((size_t)(b_i * 16 + h_i) * 1024 + t_i) * 64 + dd] = f2bf((acc[i][j][r] + bval) * scale);
        }
      } else {
#pragma unroll
        for (int r = 0; r < 4; ++r) {
          const int row = row_base + r;
          const int b_i = row >> 10, t_i = row & 1023;
          const int kk = t_i & 127;
          const int kp = ((kk >> 4) & 3) * 32 + ((kk >> 2) & 3) * 8 + ((kk >> 6) & 1) * 4 + (kk & 3);
          Co[((size_t)(b_i * 16 + h_i) * 64 + dd) * 1024 + (t_i & ~127) + kp] =
              f2bf((acc[i][j][r] + bval));
        }
      }
    }
  }
}

// ---------------- O-projection GEMM (f32 out) ----------------
__global__ __launch_bounds__(256, 4) void gemm_o(
    const unsigned short* __restrict__ A, const unsigned short* __restrict__ Bw,
    const float* __restrict__ bias, float* __restrict__ C) {
  constexpr int K = 1024, N = 1024;
  const int tid = threadIdx.x;
  const int wave = tid >> 6, lane = tid & 63;
  const int m0 = blockIdx.x * 128, n0 = blockIdx.y * 128;
  __shared__ unsigned short Asm[128 * 64];
  __shared__ unsigned short Bsm[128 * 64];
  f32x4 acc[4][4] = {};
  const int wr = (wave >> 1) * 64, wc = (wave & 1) * 64;
  const int ld_row = lane >> 3;
  const int ld_col = ((lane & 7) ^ ld_row) * 8;
  const int fr = lane & 15, g = lane >> 4;
  const int fr7 = fr & 7;

  for (int k0 = 0; k0 < K; k0 += 64) {
#pragma unroll
    for (int j = 0; j < 4; ++j) {
      const int c = j * 4 + wave;
      gld_lds16(A  + (size_t)(m0 + 8 * c + ld_row) * K + k0 + ld_col, &Asm[c * 512]);
      gld_lds16(Bw + (size_t)(n0 + 8 * c + ld_row) * K + k0 + ld_col, &Bsm[c * 512]);
    }
    __syncthreads();
#pragma unroll
    for (int ks = 0; ks < 2; ++ks) {
      const int ch = ((ks * 4 + g) ^ fr7) * 8;
      short8 af[4], bf[4];
#pragma unroll
      for (int i = 0; i < 4; ++i)
        af[i] = *(const short8*)&Asm[(wr + i * 16 + fr) * 64 + ch];
#pragma unroll
      for (int i = 0; i < 4; ++i)
        bf[i] = *(const short8*)&Bsm[(wc + i * 16 + fr) * 64 + ch];
#pragma unroll
      for (int i = 0; i < 4; ++i)
#pragma unroll
        for (int j = 0; j < 4; ++j)
          acc[i][j] = __builtin_amdgcn_mfma_f32_16x16x32_bf16(af[i], bf[j], acc[i][j], 0, 0, 0);
    }
    __syncthreads();
  }

#pragma unroll
  for (int i = 0; i < 4; ++i) {
    const int row_base = m0 + wr + i * 16 + g * 4;
#pragma unroll
    for (int j = 0; j < 4; ++j) {
      const int col = n0 + wc + j * 16 + fr;
      const float bval = bias[col];
#pragma unroll
      for (int r = 0; r < 4; ++r)
        C[(size_t)(row_base + r) * N + col] = acc[i][j][r] + bval;
    }
  }
}

// ---------------- flash attention (2-phase prefetch, register-resident P) ----------------
// Swapped QK^T: s = mfma(K, Q) -> lane(fr,g) holds S[q=fr][k=nt*16+g*4+r].
// V stored under k' so exp'd scores ARE the PV A-fragments (P never in LDS).
// l accumulated via MFMA against all-ones B; D-layout lands l[row] in the
// lane/reg owning o_acc[row] -> no shuffles.
// K/V double-buffered in LDS (64KB); next tile staged BEFORE computing current,
// with counted s_waitcnt vmcnt(8) + raw s_barrier so prefetch stays in flight
// across the barrier (T3/T4 minimum 2-phase).
__global__ __launch_bounds__(256, 2) void flash_attn(
    const unsigned short* __restrict__ Qp, const unsigned short* __restrict__ Kp,
    const unsigned short* __restrict__ Vp, const u64* __restrict__ mbits,
    unsigned short* __restrict__ O) {
  const int bh = blockIdx.x & 127, b_i = bh >> 4, h_i = bh & 15;
  const int q0 = (blockIdx.x >> 7) * 128;
  const int tid = threadIdx.x, wave = tid >> 6, lane = tid & 63;
  const unsigned short* Qb = Qp + (size_t)bh * 65536;
  const unsigned short* Kb = Kp + (size_t)bh * 65536;
  const unsigned short* Vb = Vp + (size_t)bh * 65536;
  const u64* mb = mbits + (size_t)b_i * 16384;

  __shared__ unsigned short smem[32768];   // 2 x (V[64][128] + K[128][64]) swizzled

  const int fr = lane & 15, g = lane >> 4, fr7 = fr & 7;
  const int qw = q0 + wave * 32;

  short8 qf[2][2];
#pragma unroll
  for (int mt = 0; mt < 2; ++mt)
#pragma unroll
    for (int ks = 0; ks < 2; ++ks)
      qf[mt][ks] = *(const short8*)&Qb[(size_t)(qw + mt * 16 + fr) * 64 + ks * 32 + g * 8];

  f32x4 o_acc[2][4] = {};
  f32x4 o_l[2] = {};
  const short8 ones = {0x3F80, 0x3F80, 0x3F80, 0x3F80, 0x3F80, 0x3F80, 0x3F80, 0x3F80};

  const int kld_row = lane >> 3;
  const int kld_col = ((lane & 7) ^ kld_row) * 8;                  // K swizzled fetch
  const int vld_row = lane >> 4;
  const int vld_r7w = 4 * (wave & 1) + vld_row;                    // (row&7) for V staging
  const int vld_col = ((lane & 15) ^ vld_r7w) * 8;                 // V swizzled fetch

#define STAGE(P, KT)                                                                     \
  do {                                                                                   \
    _Pragma("unroll")                                                                    \
    for (int j = 0; j < 4; ++j) {                                                        \
      const int c = j * 4 + wave;                                                        \
      gld_lds16(Kb + (size_t)((KT) + 8 * c + kld_row) * 64 + kld_col,                    \
                &smem[(P) * 16384 + 8192 + c * 512]);                                    \
      gld_lds16(Vb + (size_t)(4 * c + vld_row) * 1024 + (KT) + vld_col,                  \
                &smem[(P) * 16384 + c * 512]);                                           \
    }                                                                                    \
  } while (0)

  STAGE(0, 0);
  int p = 0;
  for (int kt = 0; kt < 1024; kt += 128) {
    if (kt < 896) {
      STAGE(p ^ 1, kt + 128);
      asm volatile("s_waitcnt vmcnt(8)" ::: "memory");   // oldest 8 (current tile) done
    } else {
      asm volatile("s_waitcnt vmcnt(0)" ::: "memory");
    }
    __builtin_amdgcn_s_barrier();
    asm volatile("" ::: "memory");
    const unsigned short* Vsm = &smem[p * 16384];
    const unsigned short* Ksm = &smem[p * 16384 + 8192];

    // mask words for this tile (L2-hit; hides under QK^T)
    const u64 w0 = mb[(size_t)(qw + fr) * 16 + (kt >> 7) * 2 + (g >> 1)];
    const u64 w1 = mb[(size_t)(qw + 16 + fr) * 16 + (kt >> 7) * 2 + (g >> 1)];

    // S^T = K Q^T  (per wave: 128 k-rows x 32 q-cols)
    f32x4 s_acc[2][8] = {};
#pragma unroll
    for (int ks = 0; ks < 2; ++ks) {
      const int ch = ((ks * 4 + g) ^ fr7) * 8;
      short8 kf[8];
#pragma unroll
      for (int nt = 0; nt < 8; ++nt)
        kf[nt] = *(const short8*)&Ksm[(nt * 16 + fr) * 64 + ch];
      __builtin_amdgcn_s_setprio(1);
#pragma unroll
      for (int mt = 0; mt < 2; ++mt)
#pragma unroll
        for (int nt = 0; nt < 8; ++nt)
          s_acc[mt][nt] = __builtin_amdgcn_mfma_f32_16x16x32_bf16(kf[nt], qf[mt][ks], s_acc[mt][nt], 0, 0, 0);
      __builtin_amdgcn_s_setprio(0);
    }

    // softmax: exp2 + mask + pack to bf16 PV-fragments, all in registers.
    short8 pf[2][4];
#pragma unroll
    for (int mt = 0; mt < 2; ++mt) {
      const u64 w = mt ? w1 : w0;
      const unsigned bits = (unsigned)(w >> ((g & 1) * 32));
#pragma unroll
      for (int ks2 = 0; ks2 < 4; ++ks2) {
        float e[8];
#pragma unroll
        for (int r = 0; r < 4; ++r) {
          float a = EXP2(s_acc[mt][ks2][r]);
          a = (bits & (1u << (ks2 * 4 + r))) ? 0.0f : a;
          float b2 = EXP2(s_acc[mt][ks2 + 4][r]);
          b2 = (bits & (1u << (16 + ks2 * 4 + r))) ? 0.0f : b2;
          e[r] = a; e[4 + r] = b2;
        }
        uint4v pk;
        pk[0] = cvt_pk_bf16(e[0], e[1]);
        pk[1] = cvt_pk_bf16(e[2], e[3]);
        pk[2] = cvt_pk_bf16(e[4], e[5]);
        pk[3] = cvt_pk_bf16(e[6], e[7]);
        union { uint4v u; short8 s; } cv; cv.u = pk;
        pf[mt][ks2] = cv.s;
      }
    }

    // O += P V ; l += P 1   (V fragments loaded once, shared across both q-tiles)
#pragma unroll
    for (int ks2 = 0; ks2 < 4; ++ks2) {
      const int cc = (ks2 * 4 + g) ^ fr7;
      short8 vf[4];
#pragma unroll
      for (int dt = 0; dt < 4; ++dt)
        vf[dt] = *(const short8*)&Vsm[(dt * 16 + fr) * 128 + cc * 8];
      __builtin_amdgcn_s_setprio(1);
#pragma unroll
      for (int mt = 0; mt < 2; ++mt) {
#pragma unroll
        for (int dt = 0; dt < 4; ++dt)
          o_acc[mt][dt] = __builtin_amdgcn_mfma_f32_16x16x32_bf16(pf[mt][ks2], vf[dt], o_acc[mt][dt], 0, 0, 0);
        o_l[mt] = __builtin_amdgcn_mfma_f32_16x16x32_bf16(pf[mt][ks2], ones, o_l[mt], 0, 0, 0);
      }
      __builtin_amdgcn_s_setprio(0);
    }
    asm volatile("" ::: "memory");
    __builtin_amdgcn_s_barrier();   // all waves done reading buf p -> safe to restage it
    p ^= 1;
  }
#undef STAGE

  // normalize and write O as (b,t,f) bf16; l is already lane-local per row.
#pragma unroll
  for (int mt = 0; mt < 2; ++mt) {
#pragma unroll
    for (int r = 0; r < 4; ++r) {
      const float inv_l = 1.0f / o_l[mt][r];
      const int qrow = qw + mt * 16 + g * 4 + r;
#pragma unroll
      for (int dt = 0; dt < 4; ++dt) {
        const int dcol = dt * 16 + fr;
        O[((size_t)(b_i * 1024 + qrow)) * 1024 + h_i * 64 + dcol] = f2bf(o_acc[mt][dt][r] * inv_l);
      }
    }
  }
}

extern "C" void kernel_launch(void* const* d_in, const int* in_sizes, int n_in,
                              void* d_out, int out_size, void* d_ws, size_t ws_size,
                              hipStream_t stream) {
  const float* query = (const float*)d_in[0];
  const float* key   = (const float*)d_in[1];
  const float* value = (const float*)d_in[2];
  const float* cosb  = (const float*)d_in[3];
  const float* sinb  = (const float*)d_in[4];
  const int*   mask  = (const int*)d_in[5];
  const float* Wq = (const float*)d_in[6];
  const float* bq = (const float*)d_in[7];
  const float* Wk = (const float*)d_in[8];
  const float* bk = (const float*)d_in[9];
  const float* Wv = (const float*)d_in[10];
  const float* bv = (const float*)d_in[11];
  const float* Wo = (const float*)d_in[12];
  const float* bo = (const float*)d_in[13];
  (void)in_sizes; (void)n_in; (void)out_size; (void)ws_size;

  char* ws = (char*)d_ws;
  const size_t MB = 1024 * 1024;
  unsigned short* q_in = (unsigned short*)(ws);
  unsigned short* k_in = (unsigned short*)(ws + 16 * MB);
  unsigned short* v_bf = (unsigned short*)(ws + 32 * MB);
  unsigned short* Qp   = (unsigned short*)(ws + 48 * MB);
  unsigned short* Kp   = (unsigned short*)(ws + 64 * MB);
  unsigned short* Vp   = (unsigned short*)(ws + 80 * MB);
  unsigned short* Wqb  = (unsigned short*)(ws + 96 * MB);
  unsigned short* Wkb  = (unsigned short*)(ws + 98 * MB);
  unsigned short* Wvb  = (unsigned short*)(ws + 100 * MB);
  unsigned short* Wob  = (unsigned short*)(ws + 102 * MB);
  u64*            mbits= (u64*)(ws + 104 * MB);
  unsigned short* attn = q_in;

  prep_kernel<<<40960, 256, 0, stream>>>(query, key, value, cosb, sinb, q_in, k_in, v_bf,
                                         mask, mbits, Wq, Wk, Wv, Wo, Wqb, Wkb, Wvb, Wob);

  dim3 blk(256);
  gemm_qkv<<<dim3(64, 8, 3), blk, 0, stream>>>(q_in, k_in, v_bf, Wqb, Wkb, Wvb,
                                               bq, bk, bv, Qp, Kp, Vp);
  flash_attn<<<1024, blk, 0, stream>>>(Qp, Kp, Vp, mbits, attn);
  gemm_o<<<dim3(64, 8), blk, 0, stream>>>(attn, Wob, bo, (float*)d_out);
}

// Round 4
// 337.056 us; speedup vs baseline: 1.0264x; 1.0264x over previous
//
#include <hip/hip_runtime.h>
#include <stdint.h>

typedef short short8 __attribute__((ext_vector_type(8)));
typedef float f32x4 __attribute__((ext_vector_type(4)));
typedef unsigned short ushort4v __attribute__((ext_vector_type(4)));
typedef unsigned int uint4v __attribute__((ext_vector_type(4)));
typedef unsigned long long u64;
typedef u64 u64x2 __attribute__((ext_vector_type(2)));

#if __has_builtin(__builtin_amdgcn_exp2f)
#define EXP2(x) __builtin_amdgcn_exp2f(x)
#else
#define EXP2(x) exp2f(x)
#endif

// f32 -> bf16 round-to-nearest-even
__device__ __forceinline__ unsigned short f2bf(float f) {
  union { float f; unsigned u; } v; v.f = f;
  unsigned r = v.u + 0x7fffu + ((v.u >> 16) & 1u);
  return (unsigned short)(r >> 16);
}

// packed f32x2 -> bf16x2 (lo -> bits[15:0], hi -> bits[31:16])
__device__ __forceinline__ unsigned cvt_pk_bf16(float lo, float hi) {
  unsigned r;
  asm("v_cvt_pk_bf16_f32 %0, %1, %2" : "=v"(r) : "v"(lo), "v"(hi));
  return r;
}

// async global->LDS, 16B per lane; lds dst is wave-uniform base + lane*16
__device__ __forceinline__ void gld_lds16(const void* g, void* l) {
  __builtin_amdgcn_global_load_lds((const __attribute__((address_space(1))) void*)g,
                                   (__attribute__((address_space(3))) void*)l, 16, 0, 0);
}

// 8 nibble-bytes (each 0..15) -> 32 packed bits (byte i -> bits [4i,4i+4))
__device__ __forceinline__ unsigned nib_compress(u64 x) {
  x = (x | (x >> 4))  & 0x00FF00FF00FF00FFull;
  x = (x | (x >> 8))  & 0x0000FFFF0000FFFFull;
  x = (x | (x >> 16));
  return (unsigned)x;
}

// ---------------- fused prep: rope+casts | mask bit-pack | weight casts ----------------
// blocks [0,4096)      : RoPE q,k -> bf16 + value f32->bf16 cast
// blocks [4096,6144)   : mask -> natural-order bit pack (one row per wave, coalesced)
// blocks [6144,10240)  : 4x weight f32->bf16 cast
//
// mask pack (natural k-order): u64 word w = (b*1024+q)*16 + h, bit j = k&63 where
// h = k>>6. flash lane(fr,g) loads the u64x2 at (qrow*16 + (kt>>6)); for score
// S[q=fr][k=kt+nt*16+g*4+r]: word = kt-half (nt<4 -> [0], nt>=4 -> [1]), bit =
// (nt&3)*16 + g*4 + r.
__global__ void prep_kernel(const float* __restrict__ q, const float* __restrict__ k,
                            const float* __restrict__ v,
                            const float* __restrict__ cs, const float* __restrict__ sn,
                            unsigned short* __restrict__ qo, unsigned short* __restrict__ ko,
                            unsigned short* __restrict__ vo,
                            const int* __restrict__ mask, u64* __restrict__ bits,
                            const float* __restrict__ s0, const float* __restrict__ s1,
                            const float* __restrict__ s2, const float* __restrict__ s3,
                            unsigned short* __restrict__ d0, unsigned short* __restrict__ d1,
                            unsigned short* __restrict__ d2, unsigned short* __restrict__ d3) {
  __shared__ unsigned mlds[256];   // 4 waves x 64 u32 nibble-bytes
  const int bx = blockIdx.x;
  if (bx < 4096) {
    const int idx = bx * 256 + threadIdx.x;
    const int p   = idx & 7;
    const int bth = idx >> 3;
    const int t   = (bth >> 4) & 1023;
    const size_t base = (size_t)bth * 64;
    const int dd0 = p * 4;

    const float4 x0 = *(const float4*)(q + base + dd0);
    const float4 x1 = *(const float4*)(q + base + dd0 + 32);
    const float4 y0 = *(const float4*)(k + base + dd0);
    const float4 y1 = *(const float4*)(k + base + dd0 + 32);
    const float4 c0 = *(const float4*)(cs + t * 64 + dd0);
    const float4 c1 = *(const float4*)(cs + t * 64 + dd0 + 32);
    const float4 sl = *(const float4*)(sn + t * 64 + dd0);
    const float4 sh = *(const float4*)(sn + t * 64 + dd0 + 32);

    ushort4v qlo, qhi, klo, khi;
    qlo[0]=f2bf(x0.x*c0.x - x1.x*sl.x); qlo[1]=f2bf(x0.y*c0.y - x1.y*sl.y);
    qlo[2]=f2bf(x0.z*c0.z - x1.z*sl.z); qlo[3]=f2bf(x0.w*c0.w - x1.w*sl.w);
    qhi[0]=f2bf(x1.x*c1.x + x0.x*sh.x); qhi[1]=f2bf(x1.y*c1.y + x0.y*sh.y);
    qhi[2]=f2bf(x1.z*c1.z + x0.z*sh.z); qhi[3]=f2bf(x1.w*c1.w + x0.w*sh.w);
    klo[0]=f2bf(y0.x*c0.x - y1.x*sl.x); klo[1]=f2bf(y0.y*c0.y - y1.y*sl.y);
    klo[2]=f2bf(y0.z*c0.z - y1.z*sl.z); klo[3]=f2bf(y0.w*c0.w - y1.w*sl.w);
    khi[0]=f2bf(y1.x*c1.x + y0.x*sh.x); khi[1]=f2bf(y1.y*c1.y + y0.y*sh.y);
    khi[2]=f2bf(y1.z*c1.z + y0.z*sh.z); khi[3]=f2bf(y1.w*c1.w + y0.w*sh.w);

    *(ushort4v*)(qo + base + dd0)      = qlo;
    *(ushort4v*)(qo + base + dd0 + 32) = qhi;
    *(ushort4v*)(ko + base + dd0)      = klo;
    *(ushort4v*)(ko + base + dd0 + 32) = khi;

    const size_t vb = (size_t)idx * 8;
    const float4 va = *(const float4*)(v + vb);
    const float4 vbv = *(const float4*)(v + vb + 4);
    ushort4v oa, ob;
    oa[0]=f2bf(va.x); oa[1]=f2bf(va.y); oa[2]=f2bf(va.z); oa[3]=f2bf(va.w);
    ob[0]=f2bf(vbv.x); ob[1]=f2bf(vbv.y); ob[2]=f2bf(vbv.z); ob[3]=f2bf(vbv.w);
    *(ushort4v*)(vo + vb)     = oa;
    *(ushort4v*)(vo + vb + 4) = ob;
  } else if (bx < 6144) {
    // one (b,q) row of 1024 mask ints per wave, fully coalesced
    const int wave = threadIdx.x >> 6, lane = threadIdx.x & 63;
    const int mrow = (bx - 4096) * 4 + wave;
    const int* mp = mask + (size_t)mrow * 1024 + lane * 16;
    const int4 a0 = *(const int4*)(mp);
    const int4 a1 = *(const int4*)(mp + 4);
    const int4 a2 = *(const int4*)(mp + 8);
    const int4 a3 = *(const int4*)(mp + 12);
    const unsigned n0 = (a0.x!=0?1u:0u)|(a0.y!=0?2u:0u)|(a0.z!=0?4u:0u)|(a0.w!=0?8u:0u);
    const unsigned n1 = (a1.x!=0?1u:0u)|(a1.y!=0?2u:0u)|(a1.z!=0?4u:0u)|(a1.w!=0?8u:0u);
    const unsigned n2 = (a2.x!=0?1u:0u)|(a2.y!=0?2u:0u)|(a2.z!=0?4u:0u)|(a2.w!=0?8u:0u);
    const unsigned n3 = (a3.x!=0?1u:0u)|(a3.y!=0?2u:0u)|(a3.z!=0?4u:0u)|(a3.w!=0?8u:0u);
    mlds[wave * 64 + lane] = n0 | (n1 << 8) | (n2 << 16) | (n3 << 24);
    // same-wave LDS dependency: compiler inserts lgkmcnt wait
    if (lane < 16) {
      const u64x2 x = ((const u64x2*)mlds)[wave * 16 + lane];
      const u64 w = (u64)nib_compress(x[0]) | ((u64)nib_compress(x[1]) << 32);
      bits[(size_t)mrow * 16 + lane] = w;
    }
  } else {
    const int idx2 = bx - 6144;
    const int m = idx2 >> 10;
    const float* src = (m == 0) ? s0 : (m == 1) ? s1 : (m == 2) ? s2 : s3;
    unsigned short* dst = (m == 0) ? d0 : (m == 1) ? d1 : (m == 2) ? d2 : d3;
    const int i = (idx2 & 1023) * 256 + threadIdx.x;
    const float4 vv = *(const float4*)(src + (size_t)i * 4);
    ushort4v o;
    o[0]=f2bf(vv.x); o[1]=f2bf(vv.y); o[2]=f2bf(vv.z); o[3]=f2bf(vv.w);
    *(ushort4v*)(dst + (size_t)i * 4) = o;
  }
}

// ---------------- merged QKV GEMM (one dispatch, z selects operand set) ----------------
// C[m,n] = (sum_k A[m,k]*B[n,k] + bias[n]) * scale
// z=0: Qp <- q_in x Wq  (scale folds 0.125*log2(e)), (b,h,t,d) bf16
// z=1: Kp <- k_in x Wk, (b,h,t,d) bf16
// z=2: Vp <- v_bf x Wv, (b,h,d,t') bf16 with t' k-permuted within 128-blocks to
//      match flash's register-resident P: k' = (nt&3)*32 + g*8 + (nt>>2)*4 + r.
__global__ __launch_bounds__(256, 4) void gemm_qkv(
    const unsigned short* __restrict__ Aq, const unsigned short* __restrict__ Ak,
    const unsigned short* __restrict__ Av,
    const unsigned short* __restrict__ Bq, const unsigned short* __restrict__ Bk,
    const unsigned short* __restrict__ Bv,
    const float* __restrict__ bq, const float* __restrict__ bk, const float* __restrict__ bv,
    unsigned short* __restrict__ Cq, unsigned short* __restrict__ Ck,
    unsigned short* __restrict__ Cv) {
  constexpr int K = 1024;
  const int z = blockIdx.z;
  const unsigned short* A  = (z == 0) ? Aq : (z == 1) ? Ak : Av;
  const unsigned short* Bw = (z == 0) ? Bq : (z == 1) ? Bk : Bv;
  const float* bias        = (z == 0) ? bq : (z == 1) ? bk : bv;
  unsigned short* Co       = (z == 0) ? Cq : (z == 1) ? Ck : Cv;
  const float scale = (z == 0) ? 0.18033688f : 1.0f;

  const int tid = threadIdx.x;
  const int wave = tid >> 6, lane = tid & 63;
  const int m0 = blockIdx.x * 128, n0 = blockIdx.y * 128;
  __shared__ unsigned short Asm[128 * 64];
  __shared__ unsigned short Bsm[128 * 64];
  f32x4 acc[4][4] = {};
  const int wr = (wave >> 1) * 64, wc = (wave & 1) * 64;
  const int ld_row = lane >> 3;
  const int ld_col = ((lane & 7) ^ ld_row) * 8;
  const int fr = lane & 15, g = lane >> 4;
  const int fr7 = fr & 7;

  for (int k0 = 0; k0 < K; k0 += 64) {
#pragma unroll
    for (int j = 0; j < 4; ++j) {
      const int c = j * 4 + wave;
      gld_lds16(A  + (size_t)(m0 + 8 * c + ld_row) * K + k0 + ld_col, &Asm[c * 512]);
      gld_lds16(Bw + (size_t)(n0 + 8 * c + ld_row) * K + k0 + ld_col, &Bsm[c * 512]);
    }
    __syncthreads();
#pragma unroll
    for (int ks = 0; ks < 2; ++ks) {
      const int ch = ((ks * 4 + g) ^ fr7) * 8;
      short8 af[4], bf[4];
#pragma unroll
      for (int i = 0; i < 4; ++i)
        af[i] = *(const short8*)&Asm[(wr + i * 16 + fr) * 64 + ch];
#pragma unroll
      for (int i = 0; i < 4; ++i)
        bf[i] = *(const short8*)&Bsm[(wc + i * 16 + fr) * 64 + ch];
#pragma unroll
      for (int i = 0; i < 4; ++i)
#pragma unroll
        for (int j = 0; j < 4; ++j)
          acc[i][j] = __builtin_amdgcn_mfma_f32_16x16x32_bf16(af[i], bf[j], acc[i][j], 0, 0, 0);
    }
    __syncthreads();
  }

#pragma unroll
  for (int i = 0; i < 4; ++i) {
    const int row_base = m0 + wr + i * 16 + g * 4;
#pragma unroll
    for (int j = 0; j < 4; ++j) {
      const int col = n0 + wc + j * 16 + fr;
      const float bval = bias[col];
      const int h_i = col >> 6, dd = col & 63;
      if (z < 2) {
#pragma unroll
        for (int r = 0; r < 4; ++r) {
          const int row = row_base + r;
          const int b_i = row >> 10, t_i = row & 1023;
          Co[((size_t)(b_i * 16 + h_i) * 1024 + t_i) * 64 + dd] = f2bf((acc[i][j][r] + bval) * scale);
        }
      } else {
#pragma unroll
        for (int r = 0; r < 4; ++r) {
          const int row = row_base + r;
          const int b_i = row >> 10, t_i = row & 1023;
          const int kk = t_i & 127;
          const int kp = ((kk >> 4) & 3) * 32 + ((kk >> 2) & 3) * 8 + ((kk >> 6) & 1) * 4 + (kk & 3);
          Co[((size_t)(b_i * 16 + h_i) * 64 + dd) * 1024 + (t_i & ~127) + kp] =
              f2bf((acc[i][j][r] + bval));
        }
      }
    }
  }
}

// ---------------- O-projection GEMM (f32 out) ----------------
__global__ __launch_bounds__(256, 4) void gemm_o(
    const unsigned short* __restrict__ A, const unsigned short* __restrict__ Bw,
    const float* __restrict__ bias, float* __restrict__ C) {
  constexpr int K = 1024, N = 1024;
  const int tid = threadIdx.x;
  const int wave = tid >> 6, lane = tid & 63;
  const int m0 = blockIdx.x * 128, n0 = blockIdx.y * 128;
  __shared__ unsigned short Asm[128 * 64];
  __shared__ unsigned short Bsm[128 * 64];
  f32x4 acc[4][4] = {};
  const int wr = (wave >> 1) * 64, wc = (wave & 1) * 64;
  const int ld_row = lane >> 3;
  const int ld_col = ((lane & 7) ^ ld_row) * 8;
  const int fr = lane & 15, g = lane >> 4;
  const int fr7 = fr & 7;

  for (int k0 = 0; k0 < K; k0 += 64) {
#pragma unroll
    for (int j = 0; j < 4; ++j) {
      const int c = j * 4 + wave;
      gld_lds16(A  + (size_t)(m0 + 8 * c + ld_row) * K + k0 + ld_col, &Asm[c * 512]);
      gld_lds16(Bw + (size_t)(n0 + 8 * c + ld_row) * K + k0 + ld_col, &Bsm[c * 512]);
    }
    __syncthreads();
#pragma unroll
    for (int ks = 0; ks < 2; ++ks) {
      const int ch = ((ks * 4 + g) ^ fr7) * 8;
      short8 af[4], bf[4];
#pragma unroll
      for (int i = 0; i < 4; ++i)
        af[i] = *(const short8*)&Asm[(wr + i * 16 + fr) * 64 + ch];
#pragma unroll
      for (int i = 0; i < 4; ++i)
        bf[i] = *(const short8*)&Bsm[(wc + i * 16 + fr) * 64 + ch];
#pragma unroll
      for (int i = 0; i < 4; ++i)
#pragma unroll
        for (int j = 0; j < 4; ++j)
          acc[i][j] = __builtin_amdgcn_mfma_f32_16x16x32_bf16(af[i], bf[j], acc[i][j], 0, 0, 0);
    }
    __syncthreads();
  }

#pragma unroll
  for (int i = 0; i < 4; ++i) {
    const int row_base = m0 + wr + i * 16 + g * 4;
#pragma unroll
    for (int j = 0; j < 4; ++j) {
      const int col = n0 + wc + j * 16 + fr;
      const float bval = bias[col];
#pragma unroll
      for (int r = 0; r < 4; ++r)
        C[(size_t)(row_base + r) * N + col] = acc[i][j][r] + bval;
    }
  }
}

// ---------------- flash attention (2-phase prefetch, register-resident P) ----------------
// Swapped QK^T: s = mfma(K, Q) -> lane(fr,g) holds S[q=fr][k=nt*16+g*4+r].
// V stored under k' so exp'd scores ARE the PV A-fragments (P never in LDS).
// l accumulated via MFMA against all-ones B; D-layout lands l[row] in the
// lane/reg owning o_acc[row] -> no shuffles.
// K/V double-buffered in LDS (64KB); next tile staged BEFORE computing current,
// with counted s_waitcnt vmcnt(8) + raw s_barrier so prefetch stays in flight
// across the barrier. Mask words for tile kt are loaded one iteration AHEAD so
// they sit between old-stage and new-stage in the vmcnt queue: the oldest-10
// wait covers [stage_cur 8][mask 2] and never drains the new stage (T3/T4).
__global__ __launch_bounds__(256, 2) void flash_attn(
    const unsigned short* __restrict__ Qp, const unsigned short* __restrict__ Kp,
    const unsigned short* __restrict__ Vp, const u64* __restrict__ mbits,
    unsigned short* __restrict__ O) {
  const int bh = blockIdx.x & 127, b_i = bh >> 4, h_i = bh & 15;
  const int q0 = (blockIdx.x >> 7) * 128;
  const int tid = threadIdx.x, wave = tid >> 6, lane = tid & 63;
  const unsigned short* Qb = Qp + (size_t)bh * 65536;
  const unsigned short* Kb = Kp + (size_t)bh * 65536;
  const unsigned short* Vb = Vp + (size_t)bh * 65536;
  const u64* mb = mbits + (size_t)b_i * 16384;

  __shared__ unsigned short smem[32768];   // 2 x (V[64][128] + K[128][64]) swizzled

  const int fr = lane & 15, g = lane >> 4, fr7 = fr & 7;
  const int shg = g * 4;
  const int qw = q0 + wave * 32;

  short8 qf[2][2];
#pragma unroll
  for (int mt = 0; mt < 2; ++mt)
#pragma unroll
    for (int ks = 0; ks < 2; ++ks)
      qf[mt][ks] = *(const short8*)&Qb[(size_t)(qw + mt * 16 + fr) * 64 + ks * 32 + g * 8];

  f32x4 o_acc[2][4] = {};
  f32x4 o_l[2] = {};
  const short8 ones = {0x3F80, 0x3F80, 0x3F80, 0x3F80, 0x3F80, 0x3F80, 0x3F80, 0x3F80};

  const int kld_row = lane >> 3;
  const int kld_col = ((lane & 7) ^ kld_row) * 8;                  // K swizzled fetch
  const int vld_row = lane >> 4;
  const int vld_r7w = 4 * (wave & 1) + vld_row;                    // (row&7) for V staging
  const int vld_col = ((lane & 15) ^ vld_r7w) * 8;                 // V swizzled fetch

#define STAGE(P, KT)                                                                     \
  do {                                                                                   \
    _Pragma("unroll")                                                                    \
    for (int j = 0; j < 4; ++j) {                                                        \
      const int c = j * 4 + wave;                                                        \
      gld_lds16(Kb + (size_t)((KT) + 8 * c + kld_row) * 64 + kld_col,                    \
                &smem[(P) * 16384 + 8192 + c * 512]);                                    \
      gld_lds16(Vb + (size_t)(4 * c + vld_row) * 1024 + (KT) + vld_col,                  \
                &smem[(P) * 16384 + c * 512]);                                           \
    }                                                                                    \
  } while (0)

  // mask words for tile 0, then first K/V stage
  u64x2 wv0 = *(const u64x2*)&mb[(size_t)(qw + fr) * 16];
  u64x2 wv1 = *(const u64x2*)&mb[(size_t)(qw + 16 + fr) * 16];
  STAGE(0, 0);
  int p = 0;
  for (int kt = 0; kt < 1024; kt += 128) {
    if (kt < 896) {
      STAGE(p ^ 1, kt + 128);
      asm volatile("s_waitcnt vmcnt(8)" ::: "memory");   // oldest 10 = cur stage + mask
    } else {
      asm volatile("s_waitcnt vmcnt(0)" ::: "memory");
    }
    __builtin_amdgcn_s_barrier();
    asm volatile("" ::: "memory");
    const unsigned short* Vsm = &smem[p * 16384];
    const unsigned short* Ksm = &smem[p * 16384 + 8192];

    // S^T = K Q^T  (per wave: 128 k-rows x 32 q-cols)
    f32x4 s_acc[2][8] = {};
#pragma unroll
    for (int ks = 0; ks < 2; ++ks) {
      const int ch = ((ks * 4 + g) ^ fr7) * 8;
      short8 kf[8];
#pragma unroll
      for (int nt = 0; nt < 8; ++nt)
        kf[nt] = *(const short8*)&Ksm[(nt * 16 + fr) * 64 + ch];
      __builtin_amdgcn_s_setprio(1);
#pragma unroll
      for (int mt = 0; mt < 2; ++mt)
#pragma unroll
        for (int nt = 0; nt < 8; ++nt)
          s_acc[mt][nt] = __builtin_amdgcn_mfma_f32_16x16x32_bf16(kf[nt], qf[mt][ks], s_acc[mt][nt], 0, 0, 0);
      __builtin_amdgcn_s_setprio(0);
    }

    // softmax: exp2 + mask + pack to bf16 PV-fragments, all in registers.
    short8 pf[2][4];
#pragma unroll
    for (int mt = 0; mt < 2; ++mt) {
      const u64 sa = (mt ? wv1[0] : wv0[0]) >> shg;
      const u64 sb = (mt ? wv1[1] : wv0[1]) >> shg;
#pragma unroll
      for (int ks2 = 0; ks2 < 4; ++ks2) {
        float e[8];
#pragma unroll
        for (int r = 0; r < 4; ++r) {
          float a = EXP2(s_acc[mt][ks2][r]);
          a = ((unsigned)(sa >> (ks2 * 16 + r)) & 1u) ? 0.0f : a;
          float b2 = EXP2(s_acc[mt][ks2 + 4][r]);
          b2 = ((unsigned)(sb >> (ks2 * 16 + r)) & 1u) ? 0.0f : b2;
          e[r] = a; e[4 + r] = b2;
        }
        uint4v pk;
        pk[0] = cvt_pk_bf16(e[0], e[1]);
        pk[1] = cvt_pk_bf16(e[2], e[3]);
        pk[2] = cvt_pk_bf16(e[4], e[5]);
        pk[3] = cvt_pk_bf16(e[6], e[7]);
        union { uint4v u; short8 s; } cv; cv.u = pk;
        pf[mt][ks2] = cv.s;
      }
    }

    // prefetch next tile's mask words (hide L2 latency under PV; wrap at end)
    {
      const int ktn = (kt + 128) & 1023;
      wv0 = *(const u64x2*)&mb[(size_t)(qw + fr) * 16 + (ktn >> 6)];
      wv1 = *(const u64x2*)&mb[(size_t)(qw + 16 + fr) * 16 + (ktn >> 6)];
    }

    // O += P V ; l += P 1   (V fragments loaded once, shared across both q-tiles)
#pragma unroll
    for (int ks2 = 0; ks2 < 4; ++ks2) {
      const int cc = (ks2 * 4 + g) ^ fr7;
      short8 vf[4];
#pragma unroll
      for (int dt = 0; dt < 4; ++dt)
        vf[dt] = *(const short8*)&Vsm[(dt * 16 + fr) * 128 + cc * 8];
      __builtin_amdgcn_s_setprio(1);
#pragma unroll
      for (int mt = 0; mt < 2; ++mt) {
#pragma unroll
        for (int dt = 0; dt < 4; ++dt)
          o_acc[mt][dt] = __builtin_amdgcn_mfma_f32_16x16x32_bf16(pf[mt][ks2], vf[dt], o_acc[mt][dt], 0, 0, 0);
        o_l[mt] = __builtin_amdgcn_mfma_f32_16x16x32_bf16(pf[mt][ks2], ones, o_l[mt], 0, 0, 0);
      }
      __builtin_amdgcn_s_setprio(0);
    }
    asm volatile("" ::: "memory");
    __builtin_amdgcn_s_barrier();   // all waves done reading buf p -> safe to restage it
    p ^= 1;
  }
#undef STAGE

  // normalize and write O as (b,t,f) bf16; l is already lane-local per row.
#pragma unroll
  for (int mt = 0; mt < 2; ++mt) {
#pragma unroll
    for (int r = 0; r < 4; ++r) {
      const float inv_l = 1.0f / o_l[mt][r];
      const int qrow = qw + mt * 16 + g * 4 + r;
#pragma unroll
      for (int dt = 0; dt < 4; ++dt) {
        const int dcol = dt * 16 + fr;
        O[((size_t)(b_i * 1024 + qrow)) * 1024 + h_i * 64 + dcol] = f2bf(o_acc[mt][dt][r] * inv_l);
      }
    }
  }
}

extern "C" void kernel_launch(void* const* d_in, const int* in_sizes, int n_in,
                              void* d_out, int out_size, void* d_ws, size_t ws_size,
                              hipStream_t stream) {
  const float* query = (const float*)d_in[0];
  const float* key   = (const float*)d_in[1];
  const float* value = (const float*)d_in[2];
  const float* cosb  = (const float*)d_in[3];
  const float* sinb  = (const float*)d_in[4];
  const int*   mask  = (const int*)d_in[5];
  const float* Wq = (const float*)d_in[6];
  const float* bq = (const float*)d_in[7];
  const float* Wk = (const float*)d_in[8];
  const float* bk = (const float*)d_in[9];
  const float* Wv = (const float*)d_in[10];
  const float* bv = (const float*)d_in[11];
  const float* Wo = (const float*)d_in[12];
  const float* bo = (const float*)d_in[13];
  (void)in_sizes; (void)n_in; (void)out_size; (void)ws_size;

  char* ws = (char*)d_ws;
  const size_t MB = 1024 * 1024;
  unsigned short* q_in = (unsigned short*)(ws);
  unsigned short* k_in = (unsigned short*)(ws + 16 * MB);
  unsigned short* v_bf = (unsigned short*)(ws + 32 * MB);
  unsigned short* Qp   = (unsigned short*)(ws + 48 * MB);
  unsigned short* Kp   = (unsigned short*)(ws + 64 * MB);
  unsigned short* Vp   = (unsigned short*)(ws + 80 * MB);
  unsigned short* Wqb  = (unsigned short*)(ws + 96 * MB);
  unsigned short* Wkb  = (unsigned short*)(ws + 98 * MB);
  unsigned short* Wvb  = (unsigned short*)(ws + 100 * MB);
  unsigned short* Wob  = (unsigned short*)(ws + 102 * MB);
  u64*            mbits= (u64*)(ws + 104 * MB);
  unsigned short* attn = q_in;

  prep_kernel<<<10240, 256, 0, stream>>>(query, key, value, cosb, sinb, q_in, k_in, v_bf,
                                         mask, mbits, Wq, Wk, Wv, Wo, Wqb, Wkb, Wvb, Wob);

  dim3 blk(256);
  gemm_qkv<<<dim3(64, 8, 3), blk, 0, stream>>>(q_in, k_in, v_bf, Wqb, Wkb, Wvb,
                                               bq, bk, bv, Qp, Kp, Vp);
  flash_attn<<<1024, blk, 0, stream>>>(Qp, Kp, Vp, mbits, attn);
  gemm_o<<<dim3(64, 8), blk, 0, stream>>>(attn, Wob, bo, (float*)d_out);
}

// Round 5
// 331.041 us; speedup vs baseline: 1.0450x; 1.0182x over previous
//
#include <hip/hip_runtime.h>
#include <stdint.h>

typedef short short8 __attribute__((ext_vector_type(8)));
typedef float f32x4 __attribute__((ext_vector_type(4)));
typedef unsigned short ushort4v __attribute__((ext_vector_type(4)));
typedef unsigned int uint4v __attribute__((ext_vector_type(4)));
typedef unsigned long long u64;
typedef u64 u64x2 __attribute__((ext_vector_type(2)));

#if __has_builtin(__builtin_amdgcn_exp2f)
#define EXP2(x) __builtin_amdgcn_exp2f(x)
#else
#define EXP2(x) exp2f(x)
#endif

// f32 -> bf16 round-to-nearest-even
__device__ __forceinline__ unsigned short f2bf(float f) {
  union { float f; unsigned u; } v; v.f = f;
  unsigned r = v.u + 0x7fffu + ((v.u >> 16) & 1u);
  return (unsigned short)(r >> 16);
}

// packed f32x2 -> bf16x2 (lo -> bits[15:0], hi -> bits[31:16]); RNE
__device__ __forceinline__ unsigned cvt_pk_bf16(float lo, float hi) {
  unsigned r;
  asm("v_cvt_pk_bf16_f32 %0, %1, %2" : "=v"(r) : "v"(lo), "v"(hi));
  return r;
}

// async global->LDS, 16B per lane; lds dst is wave-uniform base + lane*16
__device__ __forceinline__ void gld_lds16(const void* g, void* l) {
  __builtin_amdgcn_global_load_lds((const __attribute__((address_space(1))) void*)g,
                                   (__attribute__((address_space(3))) void*)l, 16, 0, 0);
}

// 8 nibble-bytes (each 0..15) -> 32 packed bits (byte i -> bits [4i,4i+4))
__device__ __forceinline__ unsigned nib_compress(u64 x) {
  x = (x | (x >> 4))  & 0x00FF00FF00FF00FFull;
  x = (x | (x >> 8))  & 0x0000FFFF0000FFFFull;
  x = (x | (x >> 16));
  return (unsigned)x;
}

// cast 32 f32 -> 32 bf16 with 16B loads/stores
__device__ __forceinline__ void cast32(const float* __restrict__ src,
                                       unsigned short* __restrict__ dst) {
  const float4 a = *(const float4*)(src);
  const float4 b = *(const float4*)(src + 4);
  const float4 c = *(const float4*)(src + 8);
  const float4 d = *(const float4*)(src + 12);
  const float4 e = *(const float4*)(src + 16);
  const float4 f = *(const float4*)(src + 20);
  const float4 g = *(const float4*)(src + 24);
  const float4 h = *(const float4*)(src + 28);
  uint4v o0, o1;
  o0[0] = cvt_pk_bf16(a.x, a.y); o0[1] = cvt_pk_bf16(a.z, a.w);
  o0[2] = cvt_pk_bf16(b.x, b.y); o0[3] = cvt_pk_bf16(b.z, b.w);
  o1[0] = cvt_pk_bf16(c.x, c.y); o1[1] = cvt_pk_bf16(c.z, c.w);
  o1[2] = cvt_pk_bf16(d.x, d.y); o1[3] = cvt_pk_bf16(d.z, d.w);
  *(uint4v*)(dst)     = o0;
  *(uint4v*)(dst + 8) = o1;
  uint4v o2, o3;
  o2[0] = cvt_pk_bf16(e.x, e.y); o2[1] = cvt_pk_bf16(e.z, e.w);
  o2[2] = cvt_pk_bf16(f.x, f.y); o2[3] = cvt_pk_bf16(f.z, f.w);
  o3[0] = cvt_pk_bf16(g.x, g.y); o3[1] = cvt_pk_bf16(g.z, g.w);
  o3[2] = cvt_pk_bf16(h.x, h.y); o3[3] = cvt_pk_bf16(h.z, h.w);
  *(uint4v*)(dst + 16) = o2;
  *(uint4v*)(dst + 24) = o3;
}

// ---------------- fused prep, grid-stride (2048 blocks, m146 streaming shape) ---------
// work-blocks [0,2048)     : RoPE q,k -> bf16 (16B stores, 16 elems/thread/stream)
// work-blocks [2048,4096)  : mask -> natural-order bit pack (one row per wave)
// work-blocks [4096,5120)  : value f32->bf16 cast (32 elems/thread)
// work-blocks [5120,5632)  : 4x weight f32->bf16 cast (32 elems/thread)
//
// mask pack (natural k-order): u64 word w = (b*1024+q)*16 + h, bit j = k&63,
// h = k>>6. flash lane(fr,g) loads the u64x2 at (qrow*16 + (kt>>6)); for score
// S[q=fr][k=kt+nt*16+g*4+r]: word = nt>>2, bit = (nt&3)*16 + g*4 + r.
__global__ void prep_kernel(const float* __restrict__ q, const float* __restrict__ k,
                            const float* __restrict__ v,
                            const float* __restrict__ cs, const float* __restrict__ sn,
                            unsigned short* __restrict__ qo, unsigned short* __restrict__ ko,
                            unsigned short* __restrict__ vo,
                            const int* __restrict__ mask, u64* __restrict__ bits,
                            const float* __restrict__ s0, const float* __restrict__ s1,
                            const float* __restrict__ s2, const float* __restrict__ s3,
                            unsigned short* __restrict__ d0, unsigned short* __restrict__ d1,
                            unsigned short* __restrict__ d2, unsigned short* __restrict__ d3) {
  __shared__ unsigned mlds[256];   // 4 waves x 64 u32 nibble-bytes
  const int tid = threadIdx.x;
  for (int wb = blockIdx.x; wb < 5632; wb += 2048) {
    if (wb < 2048) {
      // RoPE: thread covers lo-chunk [j0,j0+8) and hi-chunk [j0+32,j0+40) of one
      // (b,t,h) row for both q and k. Whole wave shares one t (cos/sin broadcast).
      const int idx = wb * 256 + tid;
      const int p   = idx & 3;
      const int bth = idx >> 2;
      const int t   = (bth >> 4) & 1023;
      const size_t base = (size_t)bth * 64;
      const int j0 = p * 8;

      const float4 c0a = *(const float4*)(cs + t * 64 + j0);
      const float4 c0b = *(const float4*)(cs + t * 64 + j0 + 4);
      const float4 c1a = *(const float4*)(cs + t * 64 + j0 + 32);
      const float4 c1b = *(const float4*)(cs + t * 64 + j0 + 36);
      const float4 s0a = *(const float4*)(sn + t * 64 + j0);
      const float4 s0b = *(const float4*)(sn + t * 64 + j0 + 4);
      const float4 s1a = *(const float4*)(sn + t * 64 + j0 + 32);
      const float4 s1b = *(const float4*)(sn + t * 64 + j0 + 36);

      const float4 x0a = *(const float4*)(q + base + j0);
      const float4 x0b = *(const float4*)(q + base + j0 + 4);
      const float4 x1a = *(const float4*)(q + base + j0 + 32);
      const float4 x1b = *(const float4*)(q + base + j0 + 36);
      uint4v qlo, qhi;
      qlo[0] = cvt_pk_bf16(x0a.x*c0a.x - x1a.x*s0a.x, x0a.y*c0a.y - x1a.y*s0a.y);
      qlo[1] = cvt_pk_bf16(x0a.z*c0a.z - x1a.z*s0a.z, x0a.w*c0a.w - x1a.w*s0a.w);
      qlo[2] = cvt_pk_bf16(x0b.x*c0b.x - x1b.x*s0b.x, x0b.y*c0b.y - x1b.y*s0b.y);
      qlo[3] = cvt_pk_bf16(x0b.z*c0b.z - x1b.z*s0b.z, x0b.w*c0b.w - x1b.w*s0b.w);
      qhi[0] = cvt_pk_bf16(x1a.x*c1a.x + x0a.x*s1a.x, x1a.y*c1a.y + x0a.y*s1a.y);
      qhi[1] = cvt_pk_bf16(x1a.z*c1a.z + x0a.z*s1a.z, x1a.w*c1a.w + x0a.w*s1a.w);
      qhi[2] = cvt_pk_bf16(x1b.x*c1b.x + x0b.x*s1b.x, x1b.y*c1b.y + x0b.y*s1b.y);
      qhi[3] = cvt_pk_bf16(x1b.z*c1b.z + x0b.z*s1b.z, x1b.w*c1b.w + x0b.w*s1b.w);
      *(uint4v*)(qo + base + j0)      = qlo;
      *(uint4v*)(qo + base + j0 + 32) = qhi;

      const float4 y0a = *(const float4*)(k + base + j0);
      const float4 y0b = *(const float4*)(k + base + j0 + 4);
      const float4 y1a = *(const float4*)(k + base + j0 + 32);
      const float4 y1b = *(const float4*)(k + base + j0 + 36);
      uint4v klo, khi;
      klo[0] = cvt_pk_bf16(y0a.x*c0a.x - y1a.x*s0a.x, y0a.y*c0a.y - y1a.y*s0a.y);
      klo[1] = cvt_pk_bf16(y0a.z*c0a.z - y1a.z*s0a.z, y0a.w*c0a.w - y1a.w*s0a.w);
      klo[2] = cvt_pk_bf16(y0b.x*c0b.x - y1b.x*s0b.x, y0b.y*c0b.y - y1b.y*s0b.y);
      klo[3] = cvt_pk_bf16(y0b.z*c0b.z - y1b.z*s0b.z, y0b.w*c0b.w - y1b.w*s0b.w);
      khi[0] = cvt_pk_bf16(y1a.x*c1a.x + y0a.x*s1a.x, y1a.y*c1a.y + y0a.y*s1a.y);
      khi[1] = cvt_pk_bf16(y1a.z*c1a.z + y0a.z*s1a.z, y1a.w*c1a.w + y0a.w*s1a.w);
      khi[2] = cvt_pk_bf16(y1b.x*c1b.x + y0b.x*s1b.x, y1b.y*c1b.y + y0b.y*s1b.y);
      khi[3] = cvt_pk_bf16(y1b.z*c1b.z + y0b.z*s1b.z, y1b.w*c1b.w + y0b.w*s1b.w);
      *(uint4v*)(ko + base + j0)      = klo;
      *(uint4v*)(ko + base + j0 + 32) = khi;
    } else if (wb < 4096) {
      // one (b,q) row of 1024 mask ints per wave, fully coalesced
      const int wave = tid >> 6, lane = tid & 63;
      const int mrow = (wb - 2048) * 4 + wave;
      const int* mp = mask + (size_t)mrow * 1024 + lane * 16;
      const int4 a0 = *(const int4*)(mp);
      const int4 a1 = *(const int4*)(mp + 4);
      const int4 a2 = *(const int4*)(mp + 8);
      const int4 a3 = *(const int4*)(mp + 12);
      const unsigned n0 = (a0.x!=0?1u:0u)|(a0.y!=0?2u:0u)|(a0.z!=0?4u:0u)|(a0.w!=0?8u:0u);
      const unsigned n1 = (a1.x!=0?1u:0u)|(a1.y!=0?2u:0u)|(a1.z!=0?4u:0u)|(a1.w!=0?8u:0u);
      const unsigned n2 = (a2.x!=0?1u:0u)|(a2.y!=0?2u:0u)|(a2.z!=0?4u:0u)|(a2.w!=0?8u:0u);
      const unsigned n3 = (a3.x!=0?1u:0u)|(a3.y!=0?2u:0u)|(a3.z!=0?4u:0u)|(a3.w!=0?8u:0u);
      mlds[wave * 64 + lane] = n0 | (n1 << 8) | (n2 << 16) | (n3 << 24);
      // same-wave LDS dependency: compiler inserts lgkmcnt wait
      if (lane < 16) {
        const u64x2 x = ((const u64x2*)mlds)[wave * 16 + lane];
        const u64 w = (u64)nib_compress(x[0]) | ((u64)nib_compress(x[1]) << 32);
        bits[(size_t)mrow * 16 + lane] = w;
      }
    } else if (wb < 5120) {
      const size_t off = ((size_t)(wb - 4096) * 256 + tid) * 32;
      cast32(v + off, vo + off);
    } else {
      const int idx2 = wb - 5120;            // [0,512): 128 work-blocks per weight
      const int m = idx2 >> 7;
      const float* src = (m == 0) ? s0 : (m == 1) ? s1 : (m == 2) ? s2 : s3;
      unsigned short* dst = (m == 0) ? d0 : (m == 1) ? d1 : (m == 2) ? d2 : d3;
      const size_t off = ((size_t)(idx2 & 127) * 256 + tid) * 32;
      cast32(src + off, dst + off);
    }
  }
}

// ---------------- merged QKV GEMM (one dispatch, z selects operand set) ----------------
// C[m,n] = (sum_k A[m,k]*B[n,k] + bias[n]) * scale
// z=0: Qp <- q_in x Wq  (scale folds 0.125*log2(e)), (b,h,t,d) bf16
// z=1: Kp <- k_in x Wk, (b,h,t,d) bf16
// z=2: Vp <- v_bf x Wv, (b,h,d,t') bf16 with t' k-permuted within 128-blocks to
//      match flash's register-resident P: k' = (nt&3)*32 + g*8 + (nt>>2)*4 + r.
__global__ __launch_bounds__(256, 4) void gemm_qkv(
    const unsigned short* __restrict__ Aq, const unsigned short* __restrict__ Ak,
    const unsigned short* __restrict__ Av,
    const unsigned short* __restrict__ Bq, const unsigned short* __restrict__ Bk,
    const unsigned short* __restrict__ Bv,
    const float* __restrict__ bq, const float* __restrict__ bk, const float* __restrict__ bv,
    unsigned short* __restrict__ Cq, unsigned short* __restrict__ Ck,
    unsigned short* __restrict__ Cv) {
  constexpr int K = 1024;
  const int z = blockIdx.z;
  const unsigned short* A  = (z == 0) ? Aq : (z == 1) ? Ak : Av;
  const unsigned short* Bw = (z == 0) ? Bq : (z == 1) ? Bk : Bv;
  const float* bias        = (z == 0) ? bq : (z == 1) ? bk : bv;
  unsigned short* Co       = (z == 0) ? Cq : (z == 1) ? Ck : Cv;
  const float scale = (z == 0) ? 0.18033688f : 1.0f;

  const int tid = threadIdx.x;
  const int wave = tid >> 6, lane = tid & 63;
  const int m0 = blockIdx.x * 128, n0 = blockIdx.y * 128;
  __shared__ unsigned short Asm[128 * 64];
  __shared__ unsigned short Bsm[128 * 64];
  f32x4 acc[4][4] = {};
  const int wr = (wave >> 1) * 64, wc = (wave & 1) * 64;
  const int ld_row = lane >> 3;
  const int ld_col = ((lane & 7) ^ ld_row) * 8;
  const int fr = lane & 15, g = lane >> 4;
  const int fr7 = fr & 7;

  for (int k0 = 0; k0 < K; k0 += 64) {
#pragma unroll
    for (int j = 0; j < 4; ++j) {
      const int c = j * 4 + wave;
      gld_lds16(A  + (size_t)(m0 + 8 * c + ld_row) * K + k0 + ld_col, &Asm[c * 512]);
      gld_lds16(Bw + (size_t)(n0 + 8 * c + ld_row) * K + k0 + ld_col, &Bsm[c * 512]);
    }
    __syncthreads();
#pragma unroll
    for (int ks = 0; ks < 2; ++ks) {
      const int ch = ((ks * 4 + g) ^ fr7) * 8;
      short8 af[4], bf[4];
#pragma unroll
      for (int i = 0; i < 4; ++i)
        af[i] = *(const short8*)&Asm[(wr + i * 16 + fr) * 64 + ch];
#pragma unroll
      for (int i = 0; i < 4; ++i)
        bf[i] = *(const short8*)&Bsm[(wc + i * 16 + fr) * 64 + ch];
#pragma unroll
      for (int i = 0; i < 4; ++i)
#pragma unroll
        for (int j = 0; j < 4; ++j)
          acc[i][j] = __builtin_amdgcn_mfma_f32_16x16x32_bf16(af[i], bf[j], acc[i][j], 0, 0, 0);
    }
    __syncthreads();
  }

#pragma unroll
  for (int i = 0; i < 4; ++i) {
    const int row_base = m0 + wr + i * 16 + g * 4;
#pragma unroll
    for (int j = 0; j < 4; ++j) {
      const int col = n0 + wc + j * 16 + fr;
      const float bval = bias[col];
      const int h_i = col >> 6, dd = col & 63;
      if (z < 2) {
#pragma unroll
        for (int r = 0; r < 4; ++r) {
          const int row = row_base + r;
          const int b_i = row >> 10, t_i = row & 1023;
          Co[((size_t)(b_i * 16 + h_i) * 1024 + t_i) * 64 + dd] = f2bf((acc[i][j][r] + bval) * scale);
        }
      } else {
#pragma unroll
        for (int r = 0; r < 4; ++r) {
          const int row = row_base + r;
          const int b_i = row >> 10, t_i = row & 1023;
          const int kk = t_i & 127;
          const int kp = ((kk >> 4) & 3) * 32 + ((kk >> 2) & 3) * 8 + ((kk >> 6) & 1) * 4 + (kk & 3);
          Co[((size_t)(b_i * 16 + h_i) * 64 + dd) * 1024 + (t_i & ~127) + kp] =
              f2bf((acc[i][j][r] + bval));
        }
      }
    }
  }
}

// ---------------- O-projection GEMM (f32 out) ----------------
__global__ __launch_bounds__(256, 4) void gemm_o(
    const unsigned short* __restrict__ A, const unsigned short* __restrict__ Bw,
    const float* __restrict__ bias, float* __restrict__ C) {
  constexpr int K = 1024, N = 1024;
  const int tid = threadIdx.x;
  const int wave = tid >> 6, lane = tid & 63;
  const int m0 = blockIdx.x * 128, n0 = blockIdx.y * 128;
  __shared__ unsigned short Asm[128 * 64];
  __shared__ unsigned short Bsm[128 * 64];
  f32x4 acc[4][4] = {};
  const int wr = (wave >> 1) * 64, wc = (wave & 1) * 64;
  const int ld_row = lane >> 3;
  const int ld_col = ((lane & 7) ^ ld_row) * 8;
  const int fr = lane & 15, g = lane >> 4;
  const int fr7 = fr & 7;

  for (int k0 = 0; k0 < K; k0 += 64) {
#pragma unroll
    for (int j = 0; j < 4; ++j) {
      const int c = j * 4 + wave;
      gld_lds16(A  + (size_t)(m0 + 8 * c + ld_row) * K + k0 + ld_col, &Asm[c * 512]);
      gld_lds16(Bw + (size_t)(n0 + 8 * c + ld_row) * K + k0 + ld_col, &Bsm[c * 512]);
    }
    __syncthreads();
#pragma unroll
    for (int ks = 0; ks < 2; ++ks) {
      const int ch = ((ks * 4 + g) ^ fr7) * 8;
      short8 af[4], bf[4];
#pragma unroll
      for (int i = 0; i < 4; ++i)
        af[i] = *(const short8*)&Asm[(wr + i * 16 + fr) * 64 + ch];
#pragma unroll
      for (int i = 0; i < 4; ++i)
        bf[i] = *(const short8*)&Bsm[(wc + i * 16 + fr) * 64 + ch];
#pragma unroll
      for (int i = 0; i < 4; ++i)
#pragma unroll
        for (int j = 0; j < 4; ++j)
          acc[i][j] = __builtin_amdgcn_mfma_f32_16x16x32_bf16(af[i], bf[j], acc[i][j], 0, 0, 0);
    }
    __syncthreads();
  }

#pragma unroll
  for (int i = 0; i < 4; ++i) {
    const int row_base = m0 + wr + i * 16 + g * 4;
#pragma unroll
    for (int j = 0; j < 4; ++j) {
      const int col = n0 + wc + j * 16 + fr;
      const float bval = bias[col];
#pragma unroll
      for (int r = 0; r < 4; ++r)
        C[(size_t)(row_base + r) * N + col] = acc[i][j][r] + bval;
    }
  }
}

// ---------------- flash attention (2-phase prefetch, register-resident P) ----------------
// Swapped QK^T: s = mfma(K, Q) -> lane(fr,g) holds S[q=fr][k=nt*16+g*4+r].
// V stored under k' so exp'd scores ARE the PV A-fragments (P never in LDS).
// l accumulated via MFMA against all-ones B; D-layout lands l[row] in the
// lane/reg owning o_acc[row] -> no shuffles.
// K/V double-buffered in LDS (64KB); next tile staged BEFORE computing current,
// with counted s_waitcnt vmcnt(8) + raw s_barrier so prefetch stays in flight
// across the barrier. Mask words for tile kt are loaded one iteration AHEAD so
// they sit between old-stage and new-stage in the vmcnt queue: the oldest-10
// wait covers [stage_cur 8][mask 2] and never drains the new stage (T3/T4).
__global__ __launch_bounds__(256, 2) void flash_attn(
    const unsigned short* __restrict__ Qp, const unsigned short* __restrict__ Kp,
    const unsigned short* __restrict__ Vp, const u64* __restrict__ mbits,
    unsigned short* __restrict__ O) {
  const int bh = blockIdx.x & 127, b_i = bh >> 4, h_i = bh & 15;
  const int q0 = (blockIdx.x >> 7) * 128;
  const int tid = threadIdx.x, wave = tid >> 6, lane = tid & 63;
  const unsigned short* Qb = Qp + (size_t)bh * 65536;
  const unsigned short* Kb = Kp + (size_t)bh * 65536;
  const unsigned short* Vb = Vp + (size_t)bh * 65536;
  const u64* mb = mbits + (size_t)b_i * 16384;

  __shared__ unsigned short smem[32768];   // 2 x (V[64][128] + K[128][64]) swizzled

  const int fr = lane & 15, g = lane >> 4, fr7 = fr & 7;
  const int shg = g * 4;
  const int qw = q0 + wave * 32;

  short8 qf[2][2];
#pragma unroll
  for (int mt = 0; mt < 2; ++mt)
#pragma unroll
    for (int ks = 0; ks < 2; ++ks)
      qf[mt][ks] = *(const short8*)&Qb[(size_t)(qw + mt * 16 + fr) * 64 + ks * 32 + g * 8];

  f32x4 o_acc[2][4] = {};
  f32x4 o_l[2] = {};
  const short8 ones = {0x3F80, 0x3F80, 0x3F80, 0x3F80, 0x3F80, 0x3F80, 0x3F80, 0x3F80};

  const int kld_row = lane >> 3;
  const int kld_col = ((lane & 7) ^ kld_row) * 8;                  // K swizzled fetch
  const int vld_row = lane >> 4;
  const int vld_r7w = 4 * (wave & 1) + vld_row;                    // (row&7) for V staging
  const int vld_col = ((lane & 15) ^ vld_r7w) * 8;                 // V swizzled fetch

#define STAGE(P, KT)                                                                     \
  do {                                                                                   \
    _Pragma("unroll")                                                                    \
    for (int j = 0; j < 4; ++j) {                                                        \
      const int c = j * 4 + wave;                                                        \
      gld_lds16(Kb + (size_t)((KT) + 8 * c + kld_row) * 64 + kld_col,                    \
                &smem[(P) * 16384 + 8192 + c * 512]);                                    \
      gld_lds16(Vb + (size_t)(4 * c + vld_row) * 1024 + (KT) + vld_col,                  \
                &smem[(P) * 16384 + c * 512]);                                           \
    }                                                                                    \
  } while (0)

  // mask words for tile 0, then first K/V stage
  u64x2 wv0 = *(const u64x2*)&mb[(size_t)(qw + fr) * 16];
  u64x2 wv1 = *(const u64x2*)&mb[(size_t)(qw + 16 + fr) * 16];
  STAGE(0, 0);
  int p = 0;
  for (int kt = 0; kt < 1024; kt += 128) {
    if (kt < 896) {
      STAGE(p ^ 1, kt + 128);
      asm volatile("s_waitcnt vmcnt(8)" ::: "memory");   // oldest 10 = cur stage + mask
    } else {
      asm volatile("s_waitcnt vmcnt(0)" ::: "memory");
    }
    __builtin_amdgcn_s_barrier();
    asm volatile("" ::: "memory");
    const unsigned short* Vsm = &smem[p * 16384];
    const unsigned short* Ksm = &smem[p * 16384 + 8192];

    // S^T = K Q^T  (per wave: 128 k-rows x 32 q-cols)
    f32x4 s_acc[2][8] = {};
#pragma unroll
    for (int ks = 0; ks < 2; ++ks) {
      const int ch = ((ks * 4 + g) ^ fr7) * 8;
      short8 kf[8];
#pragma unroll
      for (int nt = 0; nt < 8; ++nt)
        kf[nt] = *(const short8*)&Ksm[(nt * 16 + fr) * 64 + ch];
      __builtin_amdgcn_s_setprio(1);
#pragma unroll
      for (int mt = 0; mt < 2; ++mt)
#pragma unroll
        for (int nt = 0; nt < 8; ++nt)
          s_acc[mt][nt] = __builtin_amdgcn_mfma_f32_16x16x32_bf16(kf[nt], qf[mt][ks], s_acc[mt][nt], 0, 0, 0);
      __builtin_amdgcn_s_setprio(0);
    }

    // softmax: exp2 + mask + pack to bf16 PV-fragments, all in registers.
    short8 pf[2][4];
#pragma unroll
    for (int mt = 0; mt < 2; ++mt) {
      const u64 sa = (mt ? wv1[0] : wv0[0]) >> shg;
      const u64 sb = (mt ? wv1[1] : wv0[1]) >> shg;
#pragma unroll
      for (int ks2 = 0; ks2 < 4; ++ks2) {
        float e[8];
#pragma unroll
        for (int r = 0; r < 4; ++r) {
          float a = EXP2(s_acc[mt][ks2][r]);
          a = ((unsigned)(sa >> (ks2 * 16 + r)) & 1u) ? 0.0f : a;
          float b2 = EXP2(s_acc[mt][ks2 + 4][r]);
          b2 = ((unsigned)(sb >> (ks2 * 16 + r)) & 1u) ? 0.0f : b2;
          e[r] = a; e[4 + r] = b2;
        }
        uint4v pk;
        pk[0] = cvt_pk_bf16(e[0], e[1]);
        pk[1] = cvt_pk_bf16(e[2], e[3]);
        pk[2] = cvt_pk_bf16(e[4], e[5]);
        pk[3] = cvt_pk_bf16(e[6], e[7]);
        union { uint4v u; short8 s; } cv; cv.u = pk;
        pf[mt][ks2] = cv.s;
      }
    }

    // prefetch next tile's mask words (hide L2 latency under PV; wrap at end)
    {
      const int ktn = (kt + 128) & 1023;
      wv0 = *(const u64x2*)&mb[(size_t)(qw + fr) * 16 + (ktn >> 6)];
      wv1 = *(const u64x2*)&mb[(size_t)(qw + 16 + fr) * 16 + (ktn >> 6)];
    }

    // O += P V ; l += P 1   (V fragments loaded once, shared across both q-tiles)
#pragma unroll
    for (int ks2 = 0; ks2 < 4; ++ks2) {
      const int cc = (ks2 * 4 + g) ^ fr7;
      short8 vf[4];
#pragma unroll
      for (int dt = 0; dt < 4; ++dt)
        vf[dt] = *(const short8*)&Vsm[(dt * 16 + fr) * 128 + cc * 8];
      __builtin_amdgcn_s_setprio(1);
#pragma unroll
      for (int mt = 0; mt < 2; ++mt) {
#pragma unroll
        for (int dt = 0; dt < 4; ++dt)
          o_acc[mt][dt] = __builtin_amdgcn_mfma_f32_16x16x32_bf16(pf[mt][ks2], vf[dt], o_acc[mt][dt], 0, 0, 0);
        o_l[mt] = __builtin_amdgcn_mfma_f32_16x16x32_bf16(pf[mt][ks2], ones, o_l[mt], 0, 0, 0);
      }
      __builtin_amdgcn_s_setprio(0);
    }
    asm volatile("" ::: "memory");
    __builtin_amdgcn_s_barrier();   // all waves done reading buf p -> safe to restage it
    p ^= 1;
  }
#undef STAGE

  // normalize and write O as (b,t,f) bf16; l is already lane-local per row.
#pragma unroll
  for (int mt = 0; mt < 2; ++mt) {
#pragma unroll
    for (int r = 0; r < 4; ++r) {
      const float inv_l = 1.0f / o_l[mt][r];
      const int qrow = qw + mt * 16 + g * 4 + r;
#pragma unroll
      for (int dt = 0; dt < 4; ++dt) {
        const int dcol = dt * 16 + fr;
        O[((size_t)(b_i * 1024 + qrow)) * 1024 + h_i * 64 + dcol] = f2bf(o_acc[mt][dt][r] * inv_l);
      }
    }
  }
}

extern "C" void kernel_launch(void* const* d_in, const int* in_sizes, int n_in,
                              void* d_out, int out_size, void* d_ws, size_t ws_size,
                              hipStream_t stream) {
  const float* query = (const float*)d_in[0];
  const float* key   = (const float*)d_in[1];
  const float* value = (const float*)d_in[2];
  const float* cosb  = (const float*)d_in[3];
  const float* sinb  = (const float*)d_in[4];
  const int*   mask  = (const int*)d_in[5];
  const float* Wq = (const float*)d_in[6];
  const float* bq = (const float*)d_in[7];
  const float* Wk = (const float*)d_in[8];
  const float* bk = (const float*)d_in[9];
  const float* Wv = (const float*)d_in[10];
  const float* bv = (const float*)d_in[11];
  const float* Wo = (const float*)d_in[12];
  const float* bo = (const float*)d_in[13];
  (void)in_sizes; (void)n_in; (void)out_size; (void)ws_size;

  char* ws = (char*)d_ws;
  const size_t MB = 1024 * 1024;
  unsigned short* q_in = (unsigned short*)(ws);
  unsigned short* k_in = (unsigned short*)(ws + 16 * MB);
  unsigned short* v_bf = (unsigned short*)(ws + 32 * MB);
  unsigned short* Qp   = (unsigned short*)(ws + 48 * MB);
  unsigned short* Kp   = (unsigned short*)(ws + 64 * MB);
  unsigned short* Vp   = (unsigned short*)(ws + 80 * MB);
  unsigned short* Wqb  = (unsigned short*)(ws + 96 * MB);
  unsigned short* Wkb  = (unsigned short*)(ws + 98 * MB);
  unsigned short* Wvb  = (unsigned short*)(ws + 100 * MB);
  unsigned short* Wob  = (unsigned short*)(ws + 102 * MB);
  u64*            mbits= (u64*)(ws + 104 * MB);
  unsigned short* attn = q_in;

  prep_kernel<<<2048, 256, 0, stream>>>(query, key, value, cosb, sinb, q_in, k_in, v_bf,
                                        mask, mbits, Wq, Wk, Wv, Wo, Wqb, Wkb, Wvb, Wob);

  dim3 blk(256);
  gemm_qkv<<<dim3(64, 8, 3), blk, 0, stream>>>(q_in, k_in, v_bf, Wqb, Wkb, Wvb,
                                               bq, bk, bv, Qp, Kp, Vp);
  flash_attn<<<1024, blk, 0, stream>>>(Qp, Kp, Vp, mbits, attn);
  gemm_o<<<dim3(64, 8), blk, 0, stream>>>(attn, Wob, bo, (float*)d_out);
}